// Round 1
// baseline (118.113 us; speedup 1.0000x reference)
//
#include <hip/hip_runtime.h>
#include <math.h>

#define NQ   10
#define NLAY 4
#define BATCH 4096
#define HID  32
#define NM   20   // 2*NQ

// ---------------------------------------------------------------------------
// Compile-time tracking of the CNOT ring as a GF(2) linear map.
// Storage index s = A x (x = logical basis state, wire k <-> bit NQ-1-k).
// col[l][k] = A_l e_k  (xor-mask between the two storage indices a gate pairs)
// row[l][k] = row k of A_l^{-1} (parity mask giving logical bit value x_k)
// Layer l's 1q gates use snapshot l; measurement uses snapshot NLAY.
// CNOT(c,t): A <- A C  => col[c] ^= col[t];  A^-1 <- C A^-1 => row[t] ^= row[c]
// ---------------------------------------------------------------------------
struct Tables {
    unsigned col[NLAY + 1][NQ];
    unsigned row[NLAY + 1][NQ];
};

constexpr Tables make_tables() {
    Tables t{};
    unsigned col[NQ] = {}, row[NQ] = {};
    for (int k = 0; k < NQ; ++k) { col[k] = 1u << (NQ - 1 - k); row[k] = 1u << (NQ - 1 - k); }
    for (int l = 0; l <= NLAY; ++l) {
        for (int k = 0; k < NQ; ++k) { t.col[l][k] = col[k]; t.row[l][k] = row[k]; }
        for (int k = 0; k < NQ; ++k) {            // ring: CNOT(k, (k+1)%NQ)
            int c = k, tg = (k + 1) % NQ;
            col[c] ^= col[tg];
            row[tg] ^= row[c];
        }
    }
    return t;
}

static constexpr Tables TB = make_tables();

struct __align__(8) cplx { float x, y; };

__device__ __forceinline__ cplx cmul(cplx a, cplx b) {
    return { a.x * b.x - a.y * b.y, a.x * b.y + a.y * b.x };
}
__device__ __forceinline__ cplx cmad(cplx a, cplx b, cplx c) {  // a*b + c
    return { fmaf(a.x, b.x, fmaf(-a.y, b.y, c.x)),
             fmaf(a.x, b.y, fmaf( a.y, b.x, c.y)) };
}

__global__ __launch_bounds__(256) void qrh_kernel(
    const float* __restrict__ theta, const float* __restrict__ rotw,
    const float* __restrict__ escale, const float* __restrict__ ebias,
    const float* __restrict__ W1, const float* __restrict__ b1,
    const float* __restrict__ W2, const float* __restrict__ b2,
    float* __restrict__ out)
{
    __shared__ cplx ldsU[4][NLAY * NQ][4];   // [wave][gate][U00,U01,U10,U11]

    const int tid  = threadIdx.x;
    const int lane = tid & 63;
    const int wv   = tid >> 6;
    const int b    = blockIdx.x * 4 + wv;

    // ---- per-gate 2x2 unitary, computed lane-parallel (lanes 0..39) ----
    if (lane < NLAY * NQ) {
        const int g = lane, l = g / NQ, k = g % NQ;
        const float th = theta[b * NQ + k];
        const int e2 = (l * NQ + k) * 2;
        const float t0 = escale[e2 + 0] * th + ebias[e2 + 0];
        const float t1 = escale[e2 + 1] * th + ebias[e2 + 1];
        const float sn0 = sinf(0.5f * t0), c0 = cosf(0.5f * t0);
        const float sn1 = sinf(0.5f * t1), c1 = cosf(0.5f * t1);
        // U_enc = RX(t1) RZ(t0); e0 = e^{-i t0/2}
        const cplx E00 = { c1 * c0, -c1 * sn0 };
        const cplx E01 = { sn1 * sn0, -sn1 * c0 };   // -i s1 * conj(e0)
        const cplx E10 = { -sn1 * sn0, -sn1 * c0 };  // -i s1 * e0
        const cplx E11 = { c1 * c0,  c1 * sn0 };
        const int r3 = (l * NQ + k) * 3;
        const float w0 = rotw[r3 + 0], w1 = rotw[r3 + 1], w2 = rotw[r3 + 2];
        const float cw = cosf(0.5f * w1), sw = sinf(0.5f * w1);
        const float a0 = 0.5f * (w0 + w2), a1 = 0.5f * (w0 - w2);
        const float ca0 = cosf(a0), sa0 = sinf(a0);
        const float ca1 = cosf(a1), sa1 = sinf(a1);
        // U_rot = RZ(w2) RY(w1) RZ(w0)
        const cplx R00 = {  cw * ca0, -cw * sa0 };
        const cplx R01 = { -sw * ca1, -sw * sa1 };
        const cplx R10 = {  sw * ca1, -sw * sa1 };
        const cplx R11 = {  cw * ca0,  cw * sa0 };
        ldsU[wv][g][0] = cmad(R00, E00, cmul(R01, E10));
        ldsU[wv][g][1] = cmad(R00, E01, cmul(R01, E11));
        ldsU[wv][g][2] = cmad(R10, E00, cmul(R11, E10));
        ldsU[wv][g][3] = cmad(R10, E01, cmul(R11, E11));
    }
    __syncthreads();

    // ---- state: 16 complex amplitudes per lane, index = (lane<<4) | j ----
    cplx st[16];
    #pragma unroll
    for (int j = 0; j < 16; ++j) st[j] = { 0.03125f, 0.0f };  // 1/sqrt(1024)

    #pragma unroll
    for (int l = 0; l < NLAY; ++l) {
        #pragma unroll
        for (int k = 0; k < NQ; ++k) {
            const unsigned v = TB.col[l][k];    // compile-time pair mask
            const unsigned m = TB.row[l][k];    // compile-time parity mask
            const int vl = (int)(v >> 4), vj = (int)(v & 15u);
            const int ml = (int)(m >> 4), mj = (int)(m & 15u);

            const int gi = l * NQ + k;
            const cplx U00 = ldsU[wv][gi][0], U01 = ldsU[wv][gi][1];
            const cplx U10 = ldsU[wv][gi][2], U11 = ldsU[wv][gi][3];

            const int laneP = __builtin_popcount((unsigned)lane & (unsigned)ml) & 1;
            // h = x_k = laneP ^ cj ; st' = h ? U11*st + U10*pv : U00*st + U01*pv
            const cplx oc0 = laneP ? U11 : U00;   // own-coef for cj=0
            const cplx pc0 = laneP ? U10 : U01;
            const cplx oc1 = laneP ? U00 : U11;   // own-coef for cj=1
            const cplx pc1 = laneP ? U01 : U10;

            cplx pv[16];
            #pragma unroll
            for (int j = 0; j < 16; ++j) {
                cplx t = st[j ^ vj];
                if (vl) {
                    t.x = __shfl_xor(t.x, vl);
                    t.y = __shfl_xor(t.y, vl);
                }
                pv[j] = t;
            }
            #pragma unroll
            for (int j = 0; j < 16; ++j) {
                const int cj = __builtin_popcount((unsigned)(j & mj)) & 1; // folds
                const cplx oc = cj ? oc1 : oc0;
                const cplx pc = cj ? pc1 : pc0;
                st[j] = cmad(oc, st[j], cmul(pc, pv[j]));
            }
        }
    }

    // ---- measurement: feats[m] = sum_s |amp|^2 * (-1)^parity(s & M_m) ----
    float p[16];
    #pragma unroll
    for (int j = 0; j < 16; ++j) p[j] = st[j].x * st[j].x + st[j].y * st[j].y;

    float feats[NM];
    #pragma unroll
    for (int f = 0; f < NM; ++f) {
        const unsigned M = (f < NQ) ? TB.row[NLAY][f]
                                    : (TB.row[NLAY][f - NQ] ^ TB.row[NLAY][(f - NQ + 1) % NQ]);
        const int Ml = (int)(M >> 4), Mj = (int)(M & 15u);
        float s = 0.f;
        #pragma unroll
        for (int j = 0; j < 16; ++j) {
            if (__builtin_popcount((unsigned)(j & Mj)) & 1) s -= p[j]; else s += p[j];
        }
        const int lsgn = __builtin_popcount((unsigned)lane & (unsigned)Ml) & 1;
        feats[f] = lsgn ? -s : s;
    }
    #pragma unroll
    for (int sh = 1; sh < 64; sh <<= 1) {
        #pragma unroll
        for (int f = 0; f < NM; ++f) feats[f] += __shfl_xor(feats[f], sh);
    }

    // ---- MLP head: lanes 0..31 each compute one hidden unit ----
    float part = 0.f;
    if (lane < HID) {
        float acc = b1[lane];
        #pragma unroll
        for (int mm = 0; mm < NM; ++mm) acc = fmaf(feats[mm], W1[lane * NM + mm], acc);
        const float sg = 1.f / (1.f + __expf(-acc));
        part = acc * sg * W2[lane];
    }
    #pragma unroll
    for (int sh = 32; sh >= 1; sh >>= 1) part += __shfl_xor(part, sh);
    if (lane == 0) out[b] = part + b2[0];
}

extern "C" void kernel_launch(void* const* d_in, const int* in_sizes, int n_in,
                              void* d_out, int out_size, void* d_ws, size_t ws_size,
                              hipStream_t stream) {
    (void)in_sizes; (void)n_in; (void)out_size; (void)d_ws; (void)ws_size;
    const float* theta = (const float*)d_in[0];
    const float* rotw  = (const float*)d_in[1];
    const float* esc   = (const float*)d_in[2];
    const float* ebi   = (const float*)d_in[3];
    const float* W1    = (const float*)d_in[4];
    const float* b1    = (const float*)d_in[5];
    const float* W2    = (const float*)d_in[6];
    const float* b2    = (const float*)d_in[7];
    float* out = (float*)d_out;

    qrh_kernel<<<BATCH / 4, 256, 0, stream>>>(theta, rotw, esc, ebi, W1, b1, W2, b2, out);
}

// Round 2
// 111.727 us; speedup vs baseline: 1.0572x; 1.0572x over previous
//
#include <hip/hip_runtime.h>
#include <math.h>

#define NQ   10
#define NLAY 4
#define BATCH 4096
#define HID  32
#define NM   20   // 2*NQ

typedef float f2 __attribute__((ext_vector_type(2)));

// ---------------------------------------------------------------------------
// Compile-time tracking of the CNOT ring as a GF(2) linear map (see round 1).
// col[l][k] = pair-xor mask between storage indices for layer-l gate on wire k
// row[l][k] = parity mask giving logical bit x_k from storage index
// ---------------------------------------------------------------------------
struct Tables {
    unsigned col[NLAY + 1][NQ];
    unsigned row[NLAY + 1][NQ];
};

constexpr Tables make_tables() {
    Tables t{};
    unsigned col[NQ] = {}, row[NQ] = {};
    for (int k = 0; k < NQ; ++k) { col[k] = 1u << (NQ - 1 - k); row[k] = 1u << (NQ - 1 - k); }
    for (int l = 0; l <= NLAY; ++l) {
        for (int k = 0; k < NQ; ++k) { t.col[l][k] = col[k]; t.row[l][k] = row[k]; }
        for (int k = 0; k < NQ; ++k) {            // ring: CNOT(k, (k+1)%NQ)
            int c = k, tg = (k + 1) % NQ;
            col[c] ^= col[tg];
            row[tg] ^= row[c];
        }
    }
    return t;
}

static constexpr Tables TB = make_tables();

__device__ __forceinline__ f2 mk2(float a, float b) { f2 r; r[0] = a; r[1] = b; return r; }
__device__ __forceinline__ f2 ffma(f2 a, f2 b, f2 c) { return __builtin_elementwise_fma(a, b, c); }

// partner fetch: optional lane-xor shuffle (vl) then optional slot swap (vs)
__device__ __forceinline__ f2 sh2(f2 a, int vl, int vs) {
    float lo = a[0], hi = a[1];
    if (vl) { lo = __shfl_xor(lo, vl); hi = __shfl_xor(hi, vl); }
    return vs ? mk2(hi, lo) : mk2(lo, hi);
}

// st' = oc*st + pc*pv  (complex, packed over 2 amplitudes; planar re/im)
__device__ __forceinline__ f2 apply_re(f2 ox, f2 oy, f2 px, f2 py,
                                       f2 ar, f2 ai, f2 br, f2 bi) {
    return ffma(ox, ar, ffma(-oy, ai, ffma(px, br, (-py) * bi)));
}
__device__ __forceinline__ f2 apply_im(f2 ox, f2 oy, f2 px, f2 py,
                                       f2 ar, f2 ai, f2 br, f2 bi) {
    return ffma(ox, ai, ffma(oy, ar, ffma(px, bi, py * br)));
}

__global__ __launch_bounds__(256, 4) void qrh_kernel(
    const float* __restrict__ theta, const float* __restrict__ rotw,
    const float* __restrict__ escale, const float* __restrict__ ebias,
    const float* __restrict__ W1, const float* __restrict__ b1,
    const float* __restrict__ W2, const float* __restrict__ b2,
    float* __restrict__ out)
{
    // per gate: group0 = [U00.re,U00.im,U01.re,U01.im], group1 = [U11.re,U11.im,U10.re,U10.im]
    __shared__ float4 gmat[4][NLAY * NQ][2];

    const int tid  = threadIdx.x;
    const int lane = tid & 63;
    const int wv   = tid >> 6;
    const int b    = blockIdx.x * 4 + wv;

    // ---- per-gate 2x2 unitary, lane-parallel (lanes 0..39) ----
    if (lane < NLAY * NQ) {
        const int g = lane, l = g / NQ, k = g % NQ;
        const float th = theta[b * NQ + k];
        const int e2 = (l * NQ + k) * 2;
        const float t0 = escale[e2 + 0] * th + ebias[e2 + 0];
        const float t1 = escale[e2 + 1] * th + ebias[e2 + 1];
        float sn0, c0, sn1, c1;
        __sincosf(0.5f * t0, &sn0, &c0);
        __sincosf(0.5f * t1, &sn1, &c1);
        // U_enc = RX(t1) RZ(t0)
        const f2 E00 = mk2( c1 * c0,  -c1 * sn0);
        const f2 E01 = mk2( sn1 * sn0, -sn1 * c0);
        const f2 E10 = mk2(-sn1 * sn0, -sn1 * c0);
        const f2 E11 = mk2( c1 * c0,   c1 * sn0);
        const int r3 = (l * NQ + k) * 3;
        const float w0 = rotw[r3 + 0], w1 = rotw[r3 + 1], w2 = rotw[r3 + 2];
        float cw, sw, ca0, sa0, ca1, sa1;
        __sincosf(0.5f * w1, &sw, &cw);
        __sincosf(0.5f * (w0 + w2), &sa0, &ca0);
        __sincosf(0.5f * (w0 - w2), &sa1, &ca1);
        // U_rot = RZ(w2) RY(w1) RZ(w0)
        const f2 R00 = mk2( cw * ca0, -cw * sa0);
        const f2 R01 = mk2(-sw * ca1, -sw * sa1);
        const f2 R10 = mk2( sw * ca1, -sw * sa1);
        const f2 R11 = mk2( cw * ca0,  cw * sa0);
        // complex 2x2 products (scalar complex mul)
        auto cm = [](f2 a, f2 bb) { return mk2(a[0]*bb[0] - a[1]*bb[1], a[0]*bb[1] + a[1]*bb[0]); };
        const f2 U00 = cm(R00, E00) + cm(R01, E10);
        const f2 U01 = cm(R00, E01) + cm(R01, E11);
        const f2 U10 = cm(R10, E00) + cm(R11, E10);
        const f2 U11 = cm(R10, E01) + cm(R11, E11);
        gmat[wv][g][0] = make_float4(U00[0], U00[1], U01[0], U01[1]);
        gmat[wv][g][1] = make_float4(U11[0], U11[1], U10[0], U10[1]);
    }
    __syncthreads();

    // ---- state: planar re/im, 16 amps/lane packed 2-per-v2f32 ----
    // amp storage index = (lane<<4) | (r<<1) | slot
    f2 sre[8], sim[8];
    #pragma unroll
    for (int r = 0; r < 8; ++r) { sre[r] = mk2(0.03125f, 0.03125f); sim[r] = mk2(0.f, 0.f); }

    #pragma unroll
    for (int l = 0; l < NLAY; ++l) {
        #pragma unroll
        for (int k = 0; k < NQ; ++k) {
            const unsigned v = TB.col[l][k];   // compile-time
            const unsigned m = TB.row[l][k];   // compile-time
            const int vl = (int)(v >> 4), vj = (int)(v & 15u);
            const int vr = vj >> 1, vs = vj & 1;
            const int ml = (int)(m >> 4), mj = (int)(m & 15u);
            const int mjr = mj >> 1, mjs = mj & 1;
            const int gi = l * NQ + k;

            const int laneP = ml ? (__popc((unsigned)lane & (unsigned)ml) & 1) : 0;
            const float4 A = gmat[wv][gi][laneP];
            f2 oc[2], pc[2];
            oc[0] = mk2(A.x, A.y); pc[0] = mk2(A.z, A.w);
            if (mj) {
                const float4 Bq = gmat[wv][gi][laneP ^ 1];
                oc[1] = mk2(Bq.x, Bq.y); pc[1] = mk2(Bq.z, Bq.w);
            } else { oc[1] = oc[0]; pc[1] = pc[0]; }

            // packed coefficient variants; variant p used by regs with parity(r&mjr)==p
            // slot coef indices for variant p: (c0,c1) = (p, p^mjs)
            f2 ocx[2], ocy[2], pcx[2], pcy[2];
            #pragma unroll
            for (int p_ = 0; p_ < 2; ++p_) {
                const int c0 = p_, c1 = p_ ^ mjs;
                ocx[p_] = mk2(oc[c0][0], oc[c1][0]);
                ocy[p_] = mk2(oc[c0][1], oc[c1][1]);
                pcx[p_] = mk2(pc[c0][0], pc[c1][0]);
                pcy[p_] = mk2(pc[c0][1], pc[c1][1]);
            }

            #pragma unroll
            for (int r = 0; r < 8; ++r) {
                const int r2 = r ^ vr;
                if (r2 < r) continue;                 // handled jointly below
                const f2 pre_r = sh2(sre[r2], vl, vs);
                const f2 pim_r = sh2(sim[r2], vl, vs);
                const int pA = __builtin_popcount((unsigned)(r & mjr)) & 1;
                const f2 nre_r = apply_re(ocx[pA], ocy[pA], pcx[pA], pcy[pA],
                                          sre[r], sim[r], pre_r, pim_r);
                const f2 nim_r = apply_im(ocx[pA], ocy[pA], pcx[pA], pcy[pA],
                                          sre[r], sim[r], pre_r, pim_r);
                if (r2 != r) {
                    const f2 pre_2 = sh2(sre[r], vl, vs);
                    const f2 pim_2 = sh2(sim[r], vl, vs);
                    const int pB = __builtin_popcount((unsigned)(r2 & mjr)) & 1;
                    const f2 nre_2 = apply_re(ocx[pB], ocy[pB], pcx[pB], pcy[pB],
                                              sre[r2], sim[r2], pre_2, pim_2);
                    const f2 nim_2 = apply_im(ocx[pB], ocy[pB], pcx[pB], pcy[pB],
                                              sre[r2], sim[r2], pre_2, pim_2);
                    sre[r2] = nre_2; sim[r2] = nim_2;
                }
                sre[r] = nre_r; sim[r] = nim_r;
            }
        }
    }

    // ---- measurement: probs then 4-bit FWHT over register index ----
    float w[16];
    #pragma unroll
    for (int r = 0; r < 8; ++r) {
        const f2 p2 = ffma(sre[r], sre[r], sim[r] * sim[r]);
        w[2 * r] = p2[0]; w[2 * r + 1] = p2[1];
    }
    #pragma unroll
    for (int bit = 1; bit < 16; bit <<= 1) {
        #pragma unroll
        for (int j = 0; j < 16; ++j) {
            if (!(j & bit)) {
                const float a = w[j], c = w[j | bit];
                w[j] = a + c; w[j | bit] = a - c;
            }
        }
    }
    // W[t] = sum_j (-1)^{popc(j&t)} p[j]

    float feats[NM];
    #pragma unroll
    for (int f = 0; f < NM; ++f) {
        const unsigned M = (f < NQ) ? TB.row[NLAY][f]
                                    : (TB.row[NLAY][f - NQ] ^ TB.row[NLAY][(f - NQ + 1) % NQ]);
        const int Ml = (int)(M >> 4), Mj = (int)(M & 15u);
        const float s = w[Mj];
        const int lsgn = __popc((unsigned)lane & (unsigned)Ml) & 1;
        feats[f] = lsgn ? -s : s;
    }
    #pragma unroll
    for (int sh = 1; sh < 64; sh <<= 1) {
        #pragma unroll
        for (int f = 0; f < NM; ++f) feats[f] += __shfl_xor(feats[f], sh);
    }

    // ---- MLP head: lanes 0..31 each one hidden unit ----
    float part = 0.f;
    if (lane < HID) {
        float acc = b1[lane];
        #pragma unroll
        for (int mm = 0; mm < NM; ++mm) acc = fmaf(feats[mm], W1[lane * NM + mm], acc);
        const float sg = 1.f / (1.f + __expf(-acc));
        part = acc * sg * W2[lane];
    }
    #pragma unroll
    for (int sh = 32; sh >= 1; sh >>= 1) part += __shfl_xor(part, sh);
    if (lane == 0) out[b] = part + b2[0];
}

extern "C" void kernel_launch(void* const* d_in, const int* in_sizes, int n_in,
                              void* d_out, int out_size, void* d_ws, size_t ws_size,
                              hipStream_t stream) {
    (void)in_sizes; (void)n_in; (void)out_size; (void)d_ws; (void)ws_size;
    const float* theta = (const float*)d_in[0];
    const float* rotw  = (const float*)d_in[1];
    const float* esc   = (const float*)d_in[2];
    const float* ebi   = (const float*)d_in[3];
    const float* W1    = (const float*)d_in[4];
    const float* b1    = (const float*)d_in[5];
    const float* W2    = (const float*)d_in[6];
    const float* b2    = (const float*)d_in[7];
    float* out = (float*)d_out;

    qrh_kernel<<<BATCH / 4, 256, 0, stream>>>(theta, rotw, esc, ebi, W1, b1, W2, b2, out);
}